// Round 2
// baseline (991.800 us; speedup 1.0000x reference)
//
#include <hip/hip_runtime.h>
#include <stdint.h>
#include <float.h>
#include <limits.h>

// ---------------------------------------------------------------------------
// Sampler: logits = (h @ E^T + bias) / T; softmax; top-p/top-k mask;
// jax.random.categorical(key(42)) == argmax(logp + gumbel).
// Equivalence used: within the kept set, logp = scaled_logit + const(row),
// so argmax(logp+gumbel) == argmax(scaled_logit+gumbel) over the kept set.
// Kept set = prefix of (prob desc, idx asc) order: rank<k AND excl_cum<=top_p.
// k <= 63, so only the top-64 per row matter.
//
// RNG: JAX >= 0.4.36 defaults jax_threefry_partitionable=True. random_bits
// for shape (B,V), 32-bit: per-element uint64 counter i, split (hi,lo),
// threefry2x32(key=(0,42), x0=hi, x1=lo), output = out0 ^ out1.
// ---------------------------------------------------------------------------

#define TILE_V 64
#define HK 64
#define LPAD 4   // LDS row pad (floats), keeps float4 alignment (68 % 4 == 0)

__global__ __launch_bounds__(256) void logits_kernel(
    const float* __restrict__ emb,   // [V][H]
    const float* __restrict__ hs,    // [B][L][H]
    const int*   __restrict__ pos_p, // scalar
    const float* __restrict__ temps, // [B]
    const float* __restrict__ bias,  // [V]
    float*       __restrict__ out,   // [B][V] scaled logits
    int V, int H, int L)
{
    __shared__ float hsm[64][HK + LPAD];
    __shared__ float esm[TILE_V][HK + LPAD];

    const int tid = threadIdx.x;
    const int v0  = blockIdx.x * TILE_V;
    const int pos = pos_p[0];

    // loader mapping: 64 rows x 16 float4 columns
    const int lr = tid >> 4;          // 0..15 row base
    const int lc = (tid & 15) * 4;    // col (floats)
    // compute mapping: 16 (b-groups) x 16 (v-groups), 4x4 microtile
    const int tb = (tid & 15) * 4;    // batch base
    const int tv = (tid >> 4) * 4;    // vocab base (local)

    float acc[4][4] = {{0.f}};

    for (int k0 = 0; k0 < H; k0 += HK) {
#pragma unroll
        for (int i = 0; i < 4; ++i) {
            const int r = lr + 16 * i;                 // 0..63
            // hidden tile: batch r, cols k0+lc..+3
            *reinterpret_cast<float4*>(&hsm[r][lc]) =
                *reinterpret_cast<const float4*>(
                    &hs[((size_t)(r) * L + pos) * H + k0 + lc]);
            // embedding tile: vocab v0+r
            const int v = v0 + r;
            float4 ev = make_float4(0.f, 0.f, 0.f, 0.f);
            if (v < V)
                ev = *reinterpret_cast<const float4*>(
                    &emb[(size_t)v * H + k0 + lc]);
            *reinterpret_cast<float4*>(&esm[r][lc]) = ev;
        }
        __syncthreads();

#pragma unroll
        for (int k = 0; k < HK; k += 4) {
            float4 hv[4], ev[4];
#pragma unroll
            for (int i = 0; i < 4; ++i)
                hv[i] = *reinterpret_cast<const float4*>(&hsm[tb + i][k]);
#pragma unroll
            for (int j = 0; j < 4; ++j)
                ev[j] = *reinterpret_cast<const float4*>(&esm[tv + j][k]);
#pragma unroll
            for (int i = 0; i < 4; ++i)
#pragma unroll
                for (int j = 0; j < 4; ++j) {
                    acc[i][j] = fmaf(hv[i].x, ev[j].x, acc[i][j]);
                    acc[i][j] = fmaf(hv[i].y, ev[j].y, acc[i][j]);
                    acc[i][j] = fmaf(hv[i].z, ev[j].z, acc[i][j]);
                    acc[i][j] = fmaf(hv[i].w, ev[j].w, acc[i][j]);
                }
        }
        __syncthreads();
    }

#pragma unroll
    for (int i = 0; i < 4; ++i) {
        const int b = tb + i;
        const float t = temps[b];
#pragma unroll
        for (int j = 0; j < 4; ++j) {
            const int v = v0 + tv + j;
            if (v < V)
                out[(size_t)b * V + v] = (acc[i][j] + bias[v]) / t;
        }
    }
}

// ---------------------------------------------------------------------------
// JAX threefry2x32 gumbel — PARTITIONABLE path (jax_threefry_partitionable,
// default True in modern JAX). Element flat index i (< 2^32 here):
//   counter = uint64(i); x0 = hi32 = 0; x1 = lo32 = i
//   (o0, o1) = threefry2x32(key=(0,42), (x0,x1)); bits = o0 ^ o1
// ---------------------------------------------------------------------------
__device__ __forceinline__ uint32_t rotl32(uint32_t x, int d) {
    return (x << d) | (x >> (32 - d));
}

__device__ float jax_gumbel(uint32_t flat) {
    const uint32_t k0 = 0u, k1 = 42u;
    const uint32_t ks[3] = { k0, k1, k0 ^ k1 ^ 0x1BD11BDAu };
    uint32_t x0 = 0u  + ks[0];   // hi word of 64-bit counter (0: B*V < 2^32)
    uint32_t x1 = flat + ks[1];  // lo word
    const int rot[2][4] = { {13, 15, 26, 6}, {17, 29, 16, 24} };
#pragma unroll
    for (int r = 0; r < 5; ++r) {
        const int* rr = rot[r & 1];
#pragma unroll
        for (int j = 0; j < 4; ++j) {
            x0 += x1;
            x1 = rotl32(x1, rr[j]);
            x1 ^= x0;
        }
        x0 += ks[(r + 1) % 3];
        x1 += ks[(r + 2) % 3] + (uint32_t)(r + 1);
    }
    const uint32_t bits = x0 ^ x1;
    // uniform in [tiny, 1): floats in [0,1) from mantissa bits
    const uint32_t fb = (bits >> 9) | 0x3F800000u;
    const float f = __uint_as_float(fb) - 1.0f;
    const float tiny = 1.17549435e-38f;      // finfo(f32).tiny
    // (maxval - minval) rounds to exactly 1.0f; mul-then-add (exact either way)
    float u = __fadd_rn(__fmul_rn(f, 1.0f), tiny);
    u = fmaxf(tiny, u);
    const float l1 = logf(u);                // accurate log, not __logf
    return -logf(-l1);
}

// ---------------------------------------------------------------------------
// Per-batch sampling: one block per row.
// ---------------------------------------------------------------------------
#define NBINS 4096
#define CAP   2048
#define NKEEP 64

__global__ __launch_bounds__(256) void sample_kernel(
    const float* __restrict__ logits,  // [B][V] scaled
    const float* __restrict__ top_ps,  // [B]
    const int*   __restrict__ top_ks,  // [B]
    int*         __restrict__ out_ids, // [B]
    int V)
{
    const int b = blockIdx.x;
    const int tid = threadIdx.x;
    const float* row = logits + (size_t)b * V;

    __shared__ float swred[4];
    __shared__ int   bins[NBINS];
    __shared__ int   schunk[256];
    __shared__ int   sThrBin, sCnt, sMkeep;
    __shared__ float cval[CAP];
    __shared__ int   cidx[CAP];
    __shared__ float tval[NKEEP];
    __shared__ int   tidxs[NKEEP];

    // ---- pass 1: row max ----
    float m = -INFINITY;
    for (int k = tid; k < V; k += 256) m = fmaxf(m, row[k]);
#pragma unroll
    for (int o = 32; o > 0; o >>= 1) m = fmaxf(m, __shfl_xor(m, o, 64));
    if ((tid & 63) == 0) swred[tid >> 6] = m;
    __syncthreads();
    m = fmaxf(fmaxf(swred[0], swred[1]), fmaxf(swred[2], swred[3]));

    // ---- zero histogram ----
    for (int k = tid; k < NBINS; k += 256) bins[k] = 0;
    if (tid == 0) sCnt = 0;
    __syncthreads();

    // ---- pass 2: sum(exp(x-m)) + histogram of g = m - x ----
    float s = 0.f;
    for (int k = tid; k < V; k += 256) {
        const float x = row[k];
        s += expf(x - m);
        const float g = m - x;
        int bin = (int)(g * 256.0f);          // 1/256-nat bins over [0,16)
        if (bin >= NBINS) bin = NBINS - 1;    // clamp: total histogram == V
        atomicAdd(&bins[bin], 1);
    }
#pragma unroll
    for (int o = 32; o > 0; o >>= 1) s += __shfl_xor(s, o, 64);
    __syncthreads();            // bins complete; swred free for reuse
    if ((tid & 63) == 0) swred[tid >> 6] = s;

    // chunked prefix to find threshold bin (first bin where cum >= NKEEP)
    int csum = 0;
#pragma unroll
    for (int k = 0; k < NBINS / 256; ++k) csum += bins[tid * (NBINS / 256) + k];
    schunk[tid] = csum;
    __syncthreads();
    s = swred[0] + swred[1] + swred[2] + swred[3];   // full softmax denom
    if (tid == 0) {
        int cum = 0, chunk = 255;
        for (int c = 0; c < 256; ++c) {
            if (cum + schunk[c] >= NKEEP) { chunk = c; break; }
            cum += schunk[c];
        }
        int t = NBINS - 1;
        const int base = chunk * (NBINS / 256);
        for (int k = base; k < base + NBINS / 256; ++k) {
            cum += bins[k];
            if (cum >= NKEEP) { t = k; break; }
        }
        sThrBin = t;
    }
    __syncthreads();
    const int thrBin = sThrBin;

    // ---- pass 3: compact candidates (bin <= thrBin) ----
    for (int k = tid; k < V; k += 256) {
        const float x = row[k];
        const float g = m - x;
        int bin = (int)(g * 256.0f);
        if (bin >= NBINS) bin = NBINS - 1;
        if (bin <= thrBin) {
            const int p = atomicAdd(&sCnt, 1);
            if (p < CAP) { cval[p] = x; cidx[p] = k; }
        }
    }
    __syncthreads();
    const int C = min(sCnt, CAP);

    // ---- pass 4: rank-select top NKEEP (value desc, index asc; stable) ----
    for (int i = tid; i < C; i += 256) {
        const float vi = cval[i];
        const int   ii = cidx[i];
        int rank = 0;
        for (int j = 0; j < C; ++j) {
            const float vj = cval[j];
            const int   ij = cidx[j];
            rank += (vj > vi) || (vj == vi && ij < ii);
        }
        if (rank < NKEEP) { tval[rank] = vi; tidxs[rank] = ii; }
    }
    __syncthreads();

    // ---- pass 5: serial top-p/top-k cut (prefix length m) ----
    if (tid == 0) {
        const float pb = top_ps[b];
        const int   kk = top_ks[b];
        const int   nk = min(NKEEP, C);
        float cum = 0.f;
        int mk = 0;
        for (int r = 0; r < nk; ++r) {
            const float pr = expf(tval[r] - m) / s;  // softmax prob
            cum += pr;
            const float excl = cum - pr;             // ref: cum - probs_sort
            if (excl > pb || r >= kk) break;
            ++mk;
        }
        sMkeep = (mk > 0) ? mk : 1;
    }
    __syncthreads();
    const int mkeep = sMkeep;

    // ---- pass 6: gumbel argmax over kept prefix (one wave) ----
    if (tid < 64) {
        float sc = -INFINITY;
        int vid = INT_MAX;
        if (tid < mkeep) {
            const int v = tidxs[tid];
            vid = v;
            sc = tval[tid] + jax_gumbel((uint32_t)b * (uint32_t)V + (uint32_t)v);
        }
#pragma unroll
        for (int o = 32; o > 0; o >>= 1) {
            const float os = __shfl_xor(sc, o, 64);
            const int   ov = __shfl_xor(vid, o, 64);
            if (os > sc || (os == sc && ov < vid)) { sc = os; vid = ov; }
        }
        if (tid == 0) out_ids[b] = vid;
    }
}

extern "C" void kernel_launch(void* const* d_in, const int* in_sizes, int n_in,
                              void* d_out, int out_size, void* d_ws, size_t ws_size,
                              hipStream_t stream)
{
    const float* emb   = (const float*)d_in[0];
    const float* hs    = (const float*)d_in[1];
    const int*   pos   = (const int*)d_in[2];
    const float* temps = (const float*)d_in[3];
    const float* tps   = (const float*)d_in[4];
    const int*   tks   = (const int*)d_in[5];
    const float* bias  = (const float*)d_in[6];

    const int B = in_sizes[3];                     // temperatures
    const int V = in_sizes[6];                     // bias
    const int H = (int)((long long)in_sizes[0] / V);
    const int L = (int)((long long)in_sizes[1] / ((long long)B * H));

    float* logits = (float*)d_ws;                  // B*V floats (12.9 MB)

    const int nblk = (V + TILE_V - 1) / TILE_V;
    logits_kernel<<<nblk, 256, 0, stream>>>(emb, hs, pos, temps, bias,
                                            logits, V, H, L);

    sample_kernel<<<B, 256, 0, stream>>>(logits, tps, tks, (int*)d_out, V);
}

// Round 3
// 361.083 us; speedup vs baseline: 2.7467x; 2.7467x over previous
//
#include <hip/hip_runtime.h>
#include <stdint.h>
#include <float.h>
#include <limits.h>

// ---------------------------------------------------------------------------
// Sampler: logits = (h @ E^T + bias) / T; softmax; top-p/top-k mask;
// jax.random.categorical(key(42)) == argmax(logp + gumbel) over kept set.
// GEMM via bf16 MFMA with 3-term split (hi*hi + hi*lo + lo*hi): logit error
// ~2e-5 absolute << gumbel argmax margins.
// ---------------------------------------------------------------------------

typedef __bf16 bf16x8 __attribute__((ext_vector_type(8)));
typedef float  f32x4  __attribute__((ext_vector_type(4)));

#define BN 64
#define BK 64

__device__ __forceinline__ unsigned short f2bf_rn(float x) {
    uint32_t u = __float_as_uint(x);
    u += 0x7FFFu + ((u >> 16) & 1u);
    return (unsigned short)(u >> 16);
}
__device__ __forceinline__ float bf2f(unsigned short h) {
    return __uint_as_float(((uint32_t)h) << 16);
}

__global__ __launch_bounds__(256) void logits_mfma(
    const float* __restrict__ emb,   // [V][H]
    const float* __restrict__ hs,    // [B][L][H]
    const int*   __restrict__ pos_p, // scalar
    const float* __restrict__ temps, // [B]
    const float* __restrict__ bias,  // [V]
    float*       __restrict__ out,   // [B][V] scaled logits
    int V, int H, int L)
{
    __shared__ unsigned short sAhi[64 * 64];
    __shared__ unsigned short sAlo[64 * 64];
    __shared__ unsigned short sBhi[64 * 64];
    __shared__ unsigned short sBlo[64 * 64];

    const int tid = threadIdx.x;
    const int v0  = blockIdx.x * BN;
    const int pos = pos_p[0];

    // staging mapping: 32 rows x 8 chunks of 8 elems; two passes (rows +32)
    const int srow = tid >> 3;         // 0..31
    const int scol = (tid & 7) * 8;    // 0..56

    // wave tile mapping: wave w -> rows 32*(w>>1), cols 32*(w&1)
    const int lane  = tid & 63;
    const int w     = tid >> 6;
    const int rbase = (w >> 1) * 32;
    const int cbase = (w & 1) * 32;

    // LDS fragment read offsets (constant across k-steps)
    int offA[2][2], offB[2][2];
#pragma unroll
    for (int i = 0; i < 2; ++i) {
        const int ra = rbase + 16 * i + (lane & 15);
        const int rb = cbase + 16 * i + (lane & 15);
#pragma unroll
        for (int ks = 0; ks < 2; ++ks) {
            const int ke = 32 * ks + (lane >> 4) * 8;
            offA[i][ks] = ra * 64 + (ke ^ ((ra & 7) * 8));
            offB[i][ks] = rb * 64 + (ke ^ ((rb & 7) * 8));
        }
    }

    f32x4 acc[2][2];
#pragma unroll
    for (int i = 0; i < 2; ++i)
#pragma unroll
        for (int j = 0; j < 2; ++j)
            acc[i][j] = (f32x4){0.f, 0.f, 0.f, 0.f};

    float4 pB[2][2], pA[2][2];   // prefetched raw fp32 tiles

    auto issue = [&](int k0) {
#pragma unroll
        for (int p = 0; p < 2; ++p) {
            const int row = srow + 32 * p;
            const int v   = v0 + row;
            if (v < V) {
                const float* bp = emb + (size_t)v * H + (k0 + scol);
                pB[p][0] = *(const float4*)bp;
                pB[p][1] = *(const float4*)(bp + 4);
            } else {
                pB[p][0] = make_float4(0.f, 0.f, 0.f, 0.f);
                pB[p][1] = make_float4(0.f, 0.f, 0.f, 0.f);
            }
            const float* ap = hs + ((size_t)row * L + pos) * H + (k0 + scol);
            pA[p][0] = *(const float4*)ap;
            pA[p][1] = *(const float4*)(ap + 4);
        }
    };

    auto stage = [&]() {
#pragma unroll
        for (int p = 0; p < 2; ++p) {
            const int row = srow + 32 * p;
            const int off = row * 64 + (scol ^ ((row & 7) * 8));

            float fb[8] = { pB[p][0].x, pB[p][0].y, pB[p][0].z, pB[p][0].w,
                            pB[p][1].x, pB[p][1].y, pB[p][1].z, pB[p][1].w };
            float fa[8] = { pA[p][0].x, pA[p][0].y, pA[p][0].z, pA[p][0].w,
                            pA[p][1].x, pA[p][1].y, pA[p][1].z, pA[p][1].w };
            uint32_t bh[4], bl[4], ah[4], al[4];
#pragma unroll
            for (int q = 0; q < 4; ++q) {
                const unsigned short h0 = f2bf_rn(fb[2*q]);
                const unsigned short h1 = f2bf_rn(fb[2*q+1]);
                const unsigned short l0 = f2bf_rn(fb[2*q]   - bf2f(h0));
                const unsigned short l1 = f2bf_rn(fb[2*q+1] - bf2f(h1));
                bh[q] = (uint32_t)h0 | ((uint32_t)h1 << 16);
                bl[q] = (uint32_t)l0 | ((uint32_t)l1 << 16);
                const unsigned short g0 = f2bf_rn(fa[2*q]);
                const unsigned short g1 = f2bf_rn(fa[2*q+1]);
                const unsigned short m0 = f2bf_rn(fa[2*q]   - bf2f(g0));
                const unsigned short m1 = f2bf_rn(fa[2*q+1] - bf2f(g1));
                ah[q] = (uint32_t)g0 | ((uint32_t)g1 << 16);
                al[q] = (uint32_t)m0 | ((uint32_t)m1 << 16);
            }
            *(uint4*)&sBhi[off] = make_uint4(bh[0], bh[1], bh[2], bh[3]);
            *(uint4*)&sBlo[off] = make_uint4(bl[0], bl[1], bl[2], bl[3]);
            *(uint4*)&sAhi[off] = make_uint4(ah[0], ah[1], ah[2], ah[3]);
            *(uint4*)&sAlo[off] = make_uint4(al[0], al[1], al[2], al[3]);
        }
    };

    issue(0);
    for (int k0 = 0; k0 < H; k0 += BK) {
        __syncthreads();          // previous compute done (single buffer)
        stage();
        __syncthreads();          // tile visible
        if (k0 + BK < H) issue(k0 + BK);   // prefetch overlaps compute

        bf16x8 fah[2][2], fal[2][2];
#pragma unroll
        for (int i = 0; i < 2; ++i)
#pragma unroll
            for (int ks = 0; ks < 2; ++ks) {
                fah[i][ks] = *(const bf16x8*)&sAhi[offA[i][ks]];
                fal[i][ks] = *(const bf16x8*)&sAlo[offA[i][ks]];
            }
#pragma unroll
        for (int j = 0; j < 2; ++j) {
            bf16x8 fbh[2], fbl[2];
#pragma unroll
            for (int ks = 0; ks < 2; ++ks) {
                fbh[ks] = *(const bf16x8*)&sBhi[offB[j][ks]];
                fbl[ks] = *(const bf16x8*)&sBlo[offB[j][ks]];
            }
#pragma unroll
            for (int i = 0; i < 2; ++i)
#pragma unroll
                for (int ks = 0; ks < 2; ++ks) {
                    acc[i][j] = __builtin_amdgcn_mfma_f32_16x16x32_bf16(
                        fal[i][ks], fbh[ks], acc[i][j], 0, 0, 0);
                    acc[i][j] = __builtin_amdgcn_mfma_f32_16x16x32_bf16(
                        fah[i][ks], fbl[ks], acc[i][j], 0, 0, 0);
                    acc[i][j] = __builtin_amdgcn_mfma_f32_16x16x32_bf16(
                        fah[i][ks], fbh[ks], acc[i][j], 0, 0, 0);
                }
        }
    }

    // epilogue: C row = (lane>>4)*4 + reg (batch), col = lane&15 (vocab)
#pragma unroll
    for (int i = 0; i < 2; ++i)
#pragma unroll
        for (int j = 0; j < 2; ++j) {
            const int vv = v0 + cbase + 16 * j + (lane & 15);
            if (vv < V) {
                const float bv = bias[vv];
#pragma unroll
                for (int r = 0; r < 4; ++r) {
                    const int b = rbase + 16 * i + (lane >> 4) * 4 + r;
                    out[(size_t)b * V + vv] = (acc[i][j][r] + bv) / temps[b];
                }
            }
        }
}

// ---------------------------------------------------------------------------
// JAX threefry2x32 gumbel — partitionable path (verified round 2).
// ---------------------------------------------------------------------------
__device__ __forceinline__ uint32_t rotl32(uint32_t x, int d) {
    return (x << d) | (x >> (32 - d));
}

__device__ float jax_gumbel(uint32_t flat) {
    const uint32_t k0 = 0u, k1 = 42u;
    const uint32_t ks[3] = { k0, k1, k0 ^ k1 ^ 0x1BD11BDAu };
    uint32_t x0 = 0u   + ks[0];
    uint32_t x1 = flat + ks[1];
    const int rot[2][4] = { {13, 15, 26, 6}, {17, 29, 16, 24} };
#pragma unroll
    for (int r = 0; r < 5; ++r) {
        const int* rr = rot[r & 1];
#pragma unroll
        for (int j = 0; j < 4; ++j) {
            x0 += x1;
            x1 = rotl32(x1, rr[j]);
            x1 ^= x0;
        }
        x0 += ks[(r + 1) % 3];
        x1 += ks[(r + 2) % 3] + (uint32_t)(r + 1);
    }
    const uint32_t bits = x0 ^ x1;
    const uint32_t fb = (bits >> 9) | 0x3F800000u;
    const float f = __uint_as_float(fb) - 1.0f;
    const float tiny = 1.17549435e-38f;
    float u = __fadd_rn(__fmul_rn(f, 1.0f), tiny);
    u = fmaxf(tiny, u);
    const float l1 = logf(u);
    return -logf(-l1);
}

// ---------------------------------------------------------------------------
// Per-batch sampling: one block per row. (unchanged, verified round 2)
// ---------------------------------------------------------------------------
#define NBINS 4096
#define CAP   2048
#define NKEEP 64

__global__ __launch_bounds__(256) void sample_kernel(
    const float* __restrict__ logits,  // [B][V] scaled
    const float* __restrict__ top_ps,  // [B]
    const int*   __restrict__ top_ks,  // [B]
    int*         __restrict__ out_ids, // [B]
    int V)
{
    const int b = blockIdx.x;
    const int tid = threadIdx.x;
    const float* row = logits + (size_t)b * V;

    __shared__ float swred[4];
    __shared__ int   bins[NBINS];
    __shared__ int   schunk[256];
    __shared__ int   sThrBin, sCnt, sMkeep;
    __shared__ float cval[CAP];
    __shared__ int   cidx[CAP];
    __shared__ float tval[NKEEP];
    __shared__ int   tidxs[NKEEP];

    // ---- pass 1: row max ----
    float m = -INFINITY;
    for (int k = tid; k < V; k += 256) m = fmaxf(m, row[k]);
#pragma unroll
    for (int o = 32; o > 0; o >>= 1) m = fmaxf(m, __shfl_xor(m, o, 64));
    if ((tid & 63) == 0) swred[tid >> 6] = m;
    __syncthreads();
    m = fmaxf(fmaxf(swred[0], swred[1]), fmaxf(swred[2], swred[3]));

    // ---- zero histogram ----
    for (int k = tid; k < NBINS; k += 256) bins[k] = 0;
    if (tid == 0) sCnt = 0;
    __syncthreads();

    // ---- pass 2: sum(exp(x-m)) + histogram of g = m - x ----
    float s = 0.f;
    for (int k = tid; k < V; k += 256) {
        const float x = row[k];
        s += expf(x - m);
        const float g = m - x;
        int bin = (int)(g * 256.0f);
        if (bin >= NBINS) bin = NBINS - 1;
        atomicAdd(&bins[bin], 1);
    }
#pragma unroll
    for (int o = 32; o > 0; o >>= 1) s += __shfl_xor(s, o, 64);
    __syncthreads();
    if ((tid & 63) == 0) swred[tid >> 6] = s;

    int csum = 0;
#pragma unroll
    for (int k = 0; k < NBINS / 256; ++k) csum += bins[tid * (NBINS / 256) + k];
    schunk[tid] = csum;
    __syncthreads();
    s = swred[0] + swred[1] + swred[2] + swred[3];
    if (tid == 0) {
        int cum = 0, chunk = 255;
        for (int c = 0; c < 256; ++c) {
            if (cum + schunk[c] >= NKEEP) { chunk = c; break; }
            cum += schunk[c];
        }
        int t = NBINS - 1;
        const int base = chunk * (NBINS / 256);
        for (int k = base; k < base + NBINS / 256; ++k) {
            cum += bins[k];
            if (cum >= NKEEP) { t = k; break; }
        }
        sThrBin = t;
    }
    __syncthreads();
    const int thrBin = sThrBin;

    // ---- pass 3: compact candidates ----
    for (int k = tid; k < V; k += 256) {
        const float x = row[k];
        const float g = m - x;
        int bin = (int)(g * 256.0f);
        if (bin >= NBINS) bin = NBINS - 1;
        if (bin <= thrBin) {
            const int p = atomicAdd(&sCnt, 1);
            if (p < CAP) { cval[p] = x; cidx[p] = k; }
        }
    }
    __syncthreads();
    const int C = min(sCnt, CAP);

    // ---- pass 4: rank-select top NKEEP ----
    for (int i = tid; i < C; i += 256) {
        const float vi = cval[i];
        const int   ii = cidx[i];
        int rank = 0;
        for (int j = 0; j < C; ++j) {
            const float vj = cval[j];
            const int   ij = cidx[j];
            rank += (vj > vi) || (vj == vi && ij < ii);
        }
        if (rank < NKEEP) { tval[rank] = vi; tidxs[rank] = ii; }
    }
    __syncthreads();

    // ---- pass 5: serial top-p/top-k cut ----
    if (tid == 0) {
        const float pb = top_ps[b];
        const int   kk = top_ks[b];
        const int   nk = min(NKEEP, C);
        float cum = 0.f;
        int mk = 0;
        for (int r = 0; r < nk; ++r) {
            const float pr = expf(tval[r] - m) / s;
            cum += pr;
            const float excl = cum - pr;
            if (excl > pb || r >= kk) break;
            ++mk;
        }
        sMkeep = (mk > 0) ? mk : 1;
    }
    __syncthreads();
    const int mkeep = sMkeep;

    // ---- pass 6: gumbel argmax over kept prefix ----
    if (tid < 64) {
        float sc = -INFINITY;
        int vid = INT_MAX;
        if (tid < mkeep) {
            const int v = tidxs[tid];
            vid = v;
            sc = tval[tid] + jax_gumbel((uint32_t)b * (uint32_t)V + (uint32_t)v);
        }
#pragma unroll
        for (int o = 32; o > 0; o >>= 1) {
            const float os = __shfl_xor(sc, o, 64);
            const int   ov = __shfl_xor(vid, o, 64);
            if (os > sc || (os == sc && ov < vid)) { sc = os; vid = ov; }
        }
        if (tid == 0) out_ids[b] = vid;
    }
}

extern "C" void kernel_launch(void* const* d_in, const int* in_sizes, int n_in,
                              void* d_out, int out_size, void* d_ws, size_t ws_size,
                              hipStream_t stream)
{
    const float* emb   = (const float*)d_in[0];
    const float* hs    = (const float*)d_in[1];
    const int*   pos   = (const int*)d_in[2];
    const float* temps = (const float*)d_in[3];
    const float* tps   = (const float*)d_in[4];
    const int*   tks   = (const int*)d_in[5];
    const float* bias  = (const float*)d_in[6];

    const int B = in_sizes[3];                     // temperatures
    const int V = in_sizes[6];                     // bias
    const int H = (int)((long long)in_sizes[0] / V);
    const int L = (int)((long long)in_sizes[1] / ((long long)B * H));

    float* logits = (float*)d_ws;                  // B*V floats (12.9 MB)

    const int nblk = (V + BN - 1) / BN;
    logits_mfma<<<nblk, 256, 0, stream>>>(emb, hs, pos, temps, bias,
                                          logits, V, H, L);

    sample_kernel<<<B, 256, 0, stream>>>(logits, tps, tks, (int*)d_out, V);
}

// Round 4
// 354.684 us; speedup vs baseline: 2.7963x; 1.0180x over previous
//
#include <hip/hip_runtime.h>
#include <stdint.h>
#include <float.h>
#include <limits.h>

// ---------------------------------------------------------------------------
// Sampler: logits = (h @ E^T + bias) / T; softmax; top-p/top-k mask;
// jax.random.categorical(key(42)) == argmax(logp + gumbel) over kept set.
// GEMM via bf16 MFMA with 3-term split (hi*hi + hi*lo + lo*hi).
// Round 4: hw cvt_pk bf16 conversion; A (h) pre-split once into frag-ordered
// global arrays (L2-hot); B-only LDS, double-buffered, 1 barrier/K-step.
// ---------------------------------------------------------------------------

typedef __bf16 bf16x8 __attribute__((ext_vector_type(8)));
typedef float  f32x4  __attribute__((ext_vector_type(4)));

#define BN 64
#define BK 64

// pack 8 floats -> 8 bf16 hi (RNE) + 8 bf16 lo (RNE of residual)
__device__ __forceinline__ void split8(const float* f, uint4& hi, uint4& lo) {
    bf16x8 vh, vl;
#pragma unroll
    for (int e = 0; e < 8; ++e) {
        const __bf16 h = (__bf16)f[e];
        vh[e] = h;
        vl[e] = (__bf16)(f[e] - (float)h);
    }
    hi = __builtin_bit_cast(uint4, vh);
    lo = __builtin_bit_cast(uint4, vl);
}

// ---------------------------------------------------------------------------
// prep: h[b, pos, :] -> A_hi/A_lo in MFMA fragment order.
// A-frag element (verified layout): for 16-row block r16, 32-k chunk kc,
// lane = lh*16 + ll holds row (r16*16+ll), k = kc*32 + lh*8 + j, j=0..7.
// idx = ((r16*128 + kc)*64 + lh*16 + ll)*8 + j
// ---------------------------------------------------------------------------
__global__ __launch_bounds__(256) void prep_h(
    const float* __restrict__ hs, const int* __restrict__ pos_p,
    unsigned short* __restrict__ Ahi, unsigned short* __restrict__ Alo,
    int H, int L)
{
    const int pos = pos_p[0];
    const int tid = blockIdx.x * 256 + threadIdx.x;   // 16384 threads
    const int b     = tid >> 8;                       // 0..63
    const int kbase = (tid & 255) * 16;               // 0..4080
    const float* src = hs + ((size_t)b * L + pos) * H + kbase;
    float f[16];
    *(float4*)&f[0]  = *(const float4*)(src);
    *(float4*)&f[4]  = *(const float4*)(src + 4);
    *(float4*)&f[8]  = *(const float4*)(src + 8);
    *(float4*)&f[12] = *(const float4*)(src + 12);

    const int r16 = b >> 4, ll = b & 15;
    const int kc  = kbase >> 5;
    const int lh0 = (kbase >> 3) & 3;
#pragma unroll
    for (int c = 0; c < 2; ++c) {
        uint4 hi, lo;
        split8(f + 8 * c, hi, lo);
        const size_t dst = ((size_t)(r16 * 128 + kc) * 64 + (lh0 + c) * 16 + ll) * 8;
        *(uint4*)&Ahi[dst] = hi;
        *(uint4*)&Alo[dst] = lo;
    }
}

// ---------------------------------------------------------------------------
// GEMM: 64(batch) x 64(vocab) block, 4 waves of 32x32, 16x16x32 bf16 MFMA.
// ---------------------------------------------------------------------------
__global__ __launch_bounds__(256) void logits_mfma(
    const float* __restrict__ emb,              // [V][H] fp32
    const unsigned short* __restrict__ Ahi,     // frag-ordered bf16
    const unsigned short* __restrict__ Alo,
    const float* __restrict__ temps,            // [B]
    const float* __restrict__ bias,             // [V]
    float*       __restrict__ out,              // [B][V] scaled logits
    int V, int H)
{
    __shared__ unsigned short sBhi[2][64 * 64];
    __shared__ unsigned short sBlo[2][64 * 64];

    const int tid = threadIdx.x;
    const int v0  = blockIdx.x * BN;

    // B staging map: 64 rows x 4 threads, 16 fp32 each
    const int brow = tid >> 2;            // vocab row (local)
    const int bcol = (tid & 3) * 16;      // k base

    // wave tile map
    const int lane  = tid & 63;
    const int w     = tid >> 6;
    const int rbase = (w >> 1) * 32;      // batch
    const int cbase = (w & 1) * 32;       // vocab

    // B LDS read offsets (XOR-swizzled, verified round 3)
    int offB[2][2];
#pragma unroll
    for (int j = 0; j < 2; ++j) {
        const int rb = cbase + 16 * j + (lane & 15);
#pragma unroll
        for (int ks = 0; ks < 2; ++ks) {
            const int ke = 32 * ks + (lane >> 4) * 8;
            offB[j][ks] = rb * 64 + (ke ^ ((rb & 7) * 8));
        }
    }
    // B LDS write offsets (two 8-elem chunks)
    const int wswz  = (brow & 7) * 8;
    const int woff0 = brow * 64 + (bcol ^ wswz);
    const int woff1 = brow * 64 + ((bcol + 8) ^ wswz);

    // A fragment global base: idx = r16*65536 + kc*512 + lh*128 + ll*8
    size_t abase[2];
#pragma unroll
    for (int i = 0; i < 2; ++i)
        abase[i] = (size_t)((w >> 1) * 2 + i) * 65536
                 + (size_t)(lane >> 4) * 128 + (size_t)(lane & 15) * 8;

    const int vglob = v0 + brow;
    const float* bsrc = emb + (size_t)vglob * H + bcol;

    float4 pf[4];
    auto issueB = [&](int k0) {
        if (vglob < V) {
#pragma unroll
            for (int q = 0; q < 4; ++q)
                pf[q] = *(const float4*)(bsrc + k0 + 4 * q);
        } else {
#pragma unroll
            for (int q = 0; q < 4; ++q)
                pf[q] = make_float4(0.f, 0.f, 0.f, 0.f);
        }
    };
    auto stageB = [&](int buf) {
        float f[16];
        *(float4*)&f[0]  = pf[0];
        *(float4*)&f[4]  = pf[1];
        *(float4*)&f[8]  = pf[2];
        *(float4*)&f[12] = pf[3];
        uint4 h0, l0, h1, l1;
        split8(f,     h0, l0);
        split8(f + 8, h1, l1);
        *(uint4*)&sBhi[buf][woff0] = h0;
        *(uint4*)&sBlo[buf][woff0] = l0;
        *(uint4*)&sBhi[buf][woff1] = h1;
        *(uint4*)&sBlo[buf][woff1] = l1;
    };

    f32x4 acc[2][2];
#pragma unroll
    for (int i = 0; i < 2; ++i)
#pragma unroll
        for (int j = 0; j < 2; ++j)
            acc[i][j] = (f32x4){0.f, 0.f, 0.f, 0.f};

    issueB(0);
    stageB(0);
    int cur = 0;
    for (int k0 = 0; k0 < H; k0 += BK) {
        __syncthreads();                       // buf[cur] visible; buf[cur^1] free
        const bool more = (k0 + BK) < H;
        if (more) issueB(k0 + BK);             // global loads overlap compute

        const int kc = k0 >> 5;
        bf16x8 fah[2][2], fal[2][2];
#pragma unroll
        for (int i = 0; i < 2; ++i)
#pragma unroll
            for (int ks = 0; ks < 2; ++ks) {
                const size_t ai = abase[i] + (size_t)(kc + ks) * 512;
                fah[i][ks] = *(const bf16x8*)&Ahi[ai];
                fal[i][ks] = *(const bf16x8*)&Alo[ai];
            }
#pragma unroll
        for (int j = 0; j < 2; ++j) {
            bf16x8 fbh[2], fbl[2];
#pragma unroll
            for (int ks = 0; ks < 2; ++ks) {
                fbh[ks] = *(const bf16x8*)&sBhi[cur][offB[j][ks]];
                fbl[ks] = *(const bf16x8*)&sBlo[cur][offB[j][ks]];
            }
#pragma unroll
            for (int i = 0; i < 2; ++i)
#pragma unroll
                for (int ks = 0; ks < 2; ++ks) {
                    acc[i][j] = __builtin_amdgcn_mfma_f32_16x16x32_bf16(
                        fal[i][ks], fbh[ks], acc[i][j], 0, 0, 0);
                    acc[i][j] = __builtin_amdgcn_mfma_f32_16x16x32_bf16(
                        fah[i][ks], fbl[ks], acc[i][j], 0, 0, 0);
                    acc[i][j] = __builtin_amdgcn_mfma_f32_16x16x32_bf16(
                        fah[i][ks], fbh[ks], acc[i][j], 0, 0, 0);
                }
        }
        if (more) stageB(cur ^ 1);             // conversion VALU overlaps MFMA
        cur ^= 1;
    }

    // epilogue: C row = (lane>>4)*4 + reg (batch), col = lane&15 (vocab)
#pragma unroll
    for (int i = 0; i < 2; ++i)
#pragma unroll
        for (int j = 0; j < 2; ++j) {
            const int vv = v0 + cbase + 16 * j + (lane & 15);
            if (vv < V) {
                const float bv = bias[vv];
#pragma unroll
                for (int r = 0; r < 4; ++r) {
                    const int b = rbase + 16 * i + (lane >> 4) * 4 + r;
                    out[(size_t)b * V + vv] = (acc[i][j][r] + bv) / temps[b];
                }
            }
        }
}

// ---------------------------------------------------------------------------
// JAX threefry2x32 gumbel — partitionable path (verified round 2).
// ---------------------------------------------------------------------------
__device__ __forceinline__ uint32_t rotl32(uint32_t x, int d) {
    return (x << d) | (x >> (32 - d));
}

__device__ float jax_gumbel(uint32_t flat) {
    const uint32_t k0 = 0u, k1 = 42u;
    const uint32_t ks[3] = { k0, k1, k0 ^ k1 ^ 0x1BD11BDAu };
    uint32_t x0 = 0u   + ks[0];
    uint32_t x1 = flat + ks[1];
    const int rot[2][4] = { {13, 15, 26, 6}, {17, 29, 16, 24} };
#pragma unroll
    for (int r = 0; r < 5; ++r) {
        const int* rr = rot[r & 1];
#pragma unroll
        for (int j = 0; j < 4; ++j) {
            x0 += x1;
            x1 = rotl32(x1, rr[j]);
            x1 ^= x0;
        }
        x0 += ks[(r + 1) % 3];
        x1 += ks[(r + 2) % 3] + (uint32_t)(r + 1);
    }
    const uint32_t bits = x0 ^ x1;
    const uint32_t fb = (bits >> 9) | 0x3F800000u;
    const float f = __uint_as_float(fb) - 1.0f;
    const float tiny = 1.17549435e-38f;
    float u = __fadd_rn(__fmul_rn(f, 1.0f), tiny);
    u = fmaxf(tiny, u);
    const float l1 = logf(u);
    return -logf(-l1);
}

// ---------------------------------------------------------------------------
// Per-batch sampling: one block per row. (unchanged, verified round 2)
// ---------------------------------------------------------------------------
#define NBINS 4096
#define CAP   2048
#define NKEEP 64

__global__ __launch_bounds__(256) void sample_kernel(
    const float* __restrict__ logits,  // [B][V] scaled
    const float* __restrict__ top_ps,  // [B]
    const int*   __restrict__ top_ks,  // [B]
    int*         __restrict__ out_ids, // [B]
    int V)
{
    const int b = blockIdx.x;
    const int tid = threadIdx.x;
    const float* row = logits + (size_t)b * V;

    __shared__ float swred[4];
    __shared__ int   bins[NBINS];
    __shared__ int   schunk[256];
    __shared__ int   sThrBin, sCnt, sMkeep;
    __shared__ float cval[CAP];
    __shared__ int   cidx[CAP];
    __shared__ float tval[NKEEP];
    __shared__ int   tidxs[NKEEP];

    // ---- pass 1: row max ----
    float m = -INFINITY;
    for (int k = tid; k < V; k += 256) m = fmaxf(m, row[k]);
#pragma unroll
    for (int o = 32; o > 0; o >>= 1) m = fmaxf(m, __shfl_xor(m, o, 64));
    if ((tid & 63) == 0) swred[tid >> 6] = m;
    __syncthreads();
    m = fmaxf(fmaxf(swred[0], swred[1]), fmaxf(swred[2], swred[3]));

    // ---- zero histogram ----
    for (int k = tid; k < NBINS; k += 256) bins[k] = 0;
    if (tid == 0) sCnt = 0;
    __syncthreads();

    // ---- pass 2: sum(exp(x-m)) + histogram of g = m - x ----
    float s = 0.f;
    for (int k = tid; k < V; k += 256) {
        const float x = row[k];
        s += expf(x - m);
        const float g = m - x;
        int bin = (int)(g * 256.0f);
        if (bin >= NBINS) bin = NBINS - 1;
        atomicAdd(&bins[bin], 1);
    }
#pragma unroll
    for (int o = 32; o > 0; o >>= 1) s += __shfl_xor(s, o, 64);
    __syncthreads();
    if ((tid & 63) == 0) swred[tid >> 6] = s;

    int csum = 0;
#pragma unroll
    for (int k = 0; k < NBINS / 256; ++k) csum += bins[tid * (NBINS / 256) + k];
    schunk[tid] = csum;
    __syncthreads();
    s = swred[0] + swred[1] + swred[2] + swred[3];
    if (tid == 0) {
        int cum = 0, chunk = 255;
        for (int c = 0; c < 256; ++c) {
            if (cum + schunk[c] >= NKEEP) { chunk = c; break; }
            cum += schunk[c];
        }
        int t = NBINS - 1;
        const int base = chunk * (NBINS / 256);
        for (int k = base; k < base + NBINS / 256; ++k) {
            cum += bins[k];
            if (cum >= NKEEP) { t = k; break; }
        }
        sThrBin = t;
    }
    __syncthreads();
    const int thrBin = sThrBin;

    // ---- pass 3: compact candidates ----
    for (int k = tid; k < V; k += 256) {
        const float x = row[k];
        const float g = m - x;
        int bin = (int)(g * 256.0f);
        if (bin >= NBINS) bin = NBINS - 1;
        if (bin <= thrBin) {
            const int p = atomicAdd(&sCnt, 1);
            if (p < CAP) { cval[p] = x; cidx[p] = k; }
        }
    }
    __syncthreads();
    const int C = min(sCnt, CAP);

    // ---- pass 4: rank-select top NKEEP ----
    for (int i = tid; i < C; i += 256) {
        const float vi = cval[i];
        const int   ii = cidx[i];
        int rank = 0;
        for (int j = 0; j < C; ++j) {
            const float vj = cval[j];
            const int   ij = cidx[j];
            rank += (vj > vi) || (vj == vi && ij < ii);
        }
        if (rank < NKEEP) { tval[rank] = vi; tidxs[rank] = ii; }
    }
    __syncthreads();

    // ---- pass 5: serial top-p/top-k cut ----
    if (tid == 0) {
        const float pb = top_ps[b];
        const int   kk = top_ks[b];
        const int   nk = min(NKEEP, C);
        float cum = 0.f;
        int mk = 0;
        for (int r = 0; r < nk; ++r) {
            const float pr = expf(tval[r] - m) / s;
            cum += pr;
            const float excl = cum - pr;
            if (excl > pb || r >= kk) break;
            ++mk;
        }
        sMkeep = (mk > 0) ? mk : 1;
    }
    __syncthreads();
    const int mkeep = sMkeep;

    // ---- pass 6: gumbel argmax over kept prefix ----
    if (tid < 64) {
        float sc = -INFINITY;
        int vid = INT_MAX;
        if (tid < mkeep) {
            const int v = tidxs[tid];
            vid = v;
            sc = tval[tid] + jax_gumbel((uint32_t)b * (uint32_t)V + (uint32_t)v);
        }
#pragma unroll
        for (int o = 32; o > 0; o >>= 1) {
            const float os = __shfl_xor(sc, o, 64);
            const int   ov = __shfl_xor(vid, o, 64);
            if (os > sc || (os == sc && ov < vid)) { sc = os; vid = ov; }
        }
        if (tid == 0) out_ids[b] = vid;
    }
}

extern "C" void kernel_launch(void* const* d_in, const int* in_sizes, int n_in,
                              void* d_out, int out_size, void* d_ws, size_t ws_size,
                              hipStream_t stream)
{
    const float* emb   = (const float*)d_in[0];
    const float* hs    = (const float*)d_in[1];
    const int*   pos   = (const int*)d_in[2];
    const float* temps = (const float*)d_in[3];
    const float* tps   = (const float*)d_in[4];
    const int*   tks   = (const int*)d_in[5];
    const float* bias  = (const float*)d_in[6];

    const int B = in_sizes[3];                     // temperatures
    const int V = in_sizes[6];                     // bias
    const int H = (int)((long long)in_sizes[0] / V);
    const int L = (int)((long long)in_sizes[1] / ((long long)B * H));

    float*          logits = (float*)d_ws;                        // B*V fp32
    unsigned short* Ahi    = (unsigned short*)((char*)d_ws + (16u << 20));
    unsigned short* Alo    = Ahi + (size_t)B * H;                 // 512 KB each

    prep_h<<<(B * H) / (16 * 256), 256, 0, stream>>>(hs, pos, Ahi, Alo, H, L);

    const int nblk = (V + BN - 1) / BN;
    logits_mfma<<<nblk, 256, 0, stream>>>(emb, Ahi, Alo, temps, bias,
                                          logits, V, H);

    sample_kernel<<<B, 256, 0, stream>>>(logits, tps, tks, (int*)d_out, V);
}